// Round 1
// baseline (2345.356 us; speedup 1.0000x reference)
//
#include <hip/hip_runtime.h>
#include <math.h>

// ---------------------------------------------------------------------------
// VertexGNN on MI355X — fp32 baseline, wave-per-row (wave=64 == H=64).
// Pipeline: node_embed -> deg -> 3x(memset agg; edge_msg+scatter; node_update)
//           -> pool -> head.
// ---------------------------------------------------------------------------

__device__ __forceinline__ float wave_sum64(float v) {
#pragma unroll
  for (int m = 1; m < 64; m <<= 1) v += __shfl_xor(v, m, 64);
  return v;
}

// LayerNorm across the 64 lanes of a wave (population variance, eps=1e-5).
__device__ __forceinline__ float ln_apply(float t, float g, float b) {
  float mu = wave_sum64(t) * 0.015625f;          // /64
  float d = t - mu;
  float var = wave_sum64(d * d) * 0.015625f;     // /64
  return d * rsqrtf(var + 1e-5f) * g + b;
}

__device__ __forceinline__ float gelu_exact(float v) {
  return 0.5f * v * (1.0f + erff(v * 0.70710678118654752440f));
}

// Broadcast lane k's value to all lanes (k compile-time const, full exec mask).
__device__ __forceinline__ float lane_bcast(float v, int k) {
  return __uint_as_float(__builtin_amdgcn_readlane(__float_as_uint(v), k));
}

// --------------------------- node embedding --------------------------------
// h = gelu(ln(gelu(ln(x@W1+b1))@W2+b2)); one wave per node, grid-stride.
__global__ void k_node_embed(const float* __restrict__ x,
                             const float* __restrict__ w1, const float* __restrict__ b1,
                             const float* __restrict__ g1, const float* __restrict__ be1,
                             const float* __restrict__ w2, const float* __restrict__ b2,
                             const float* __restrict__ g2, const float* __restrict__ be2,
                             float* __restrict__ h, int n_nodes) {
  const int lane = threadIdx.x & 63;
  const int wid = (blockIdx.x * blockDim.x + threadIdx.x) >> 6;
  const int nw = (gridDim.x * blockDim.x) >> 6;
  float wc[64];  // column `lane` of W2, preloaded (amortized over grid-stride)
#pragma unroll
  for (int k = 0; k < 64; k++) wc[k] = w2[k * 64 + lane];
  const float w1a = w1[lane], w1b = w1[64 + lane];
  const float vb1 = b1[lane], vg1 = g1[lane], vbe1 = be1[lane];
  const float vb2 = b2[lane], vg2 = g2[lane], vbe2 = be2[lane];
  for (int n = wid; n < n_nodes; n += nw) {
    const float x0 = x[2 * n], x1 = x[2 * n + 1];
    float t = fmaf(x0, w1a, fmaf(x1, w1b, vb1));
    t = gelu_exact(ln_apply(t, vg1, vbe1));
    float a0 = vb2, a1 = 0.f, a2 = 0.f, a3 = 0.f;
#pragma unroll
    for (int k = 0; k < 64; k += 4) {
      a0 = fmaf(lane_bcast(t, k + 0), wc[k + 0], a0);
      a1 = fmaf(lane_bcast(t, k + 1), wc[k + 1], a1);
      a2 = fmaf(lane_bcast(t, k + 2), wc[k + 2], a2);
      a3 = fmaf(lane_bcast(t, k + 3), wc[k + 3], a3);
    }
    float acc = (a0 + a1) + (a2 + a3);
    acc = gelu_exact(ln_apply(acc, vg2, vbe2));
    h[n * 64 + lane] = acc;
  }
}

// ------------------------------ degree -------------------------------------
__global__ void k_deg(const int* __restrict__ ei, float* __restrict__ deg, int ne) {
  int i = blockIdx.x * blockDim.x + threadIdx.x;
  if (i < ne) atomicAdd(&deg[ei[ne + i]], 1.0f);
}

// --------------------- edge message + scatter-add --------------------------
// msg = gelu(ln(concat(h[src], ea) @ W + b)); atomicAdd into agg[dst].
// One wave per edge, grid-stride; W column (66 floats) held in VGPRs.
__global__ void k_edge(const float* __restrict__ h, const float* __restrict__ ea,
                       const int* __restrict__ ei, const float* __restrict__ W,
                       const float* __restrict__ bias, const float* __restrict__ mg,
                       const float* __restrict__ mb, float* __restrict__ agg, int ne) {
  const int lane = threadIdx.x & 63;
  const int wid = (blockIdx.x * blockDim.x + threadIdx.x) >> 6;
  const int nw = (gridDim.x * blockDim.x) >> 6;
  float wc[66];
#pragma unroll
  for (int k = 0; k < 66; k++) wc[k] = W[k * 64 + lane];
  const float vb = bias[lane], vg = mg[lane], vmb = mb[lane];
  for (int e = wid; e < ne; e += nw) {
    const int s = ei[e];
    const int d = ei[ne + e];
    const float hv = h[s * 64 + lane];
    const float e0 = ea[2 * e], e1 = ea[2 * e + 1];
    float a0 = vb, a1 = 0.f, a2 = 0.f, a3 = 0.f;
#pragma unroll
    for (int k = 0; k < 64; k += 4) {
      a0 = fmaf(lane_bcast(hv, k + 0), wc[k + 0], a0);
      a1 = fmaf(lane_bcast(hv, k + 1), wc[k + 1], a1);
      a2 = fmaf(lane_bcast(hv, k + 2), wc[k + 2], a2);
      a3 = fmaf(lane_bcast(hv, k + 3), wc[k + 3], a3);
    }
    a0 = fmaf(e0, wc[64], a0);
    a1 = fmaf(e1, wc[65], a1);
    float acc = (a0 + a1) + (a2 + a3);
    acc = gelu_exact(ln_apply(acc, vg, vmb));
    atomicAdd(&agg[d * 64 + lane], acc);
  }
}

// --------------------------- node update -----------------------------------
// conv_out = ln(agg/deg + h); h += ln(conv_out). One wave per node.
__global__ void k_node_update(float* __restrict__ h, const float* __restrict__ agg,
                              const float* __restrict__ deg,
                              const float* __restrict__ ng, const float* __restrict__ nb,
                              const float* __restrict__ og, const float* __restrict__ ob,
                              int n_nodes) {
  const int lane = threadIdx.x & 63;
  const int n = (blockIdx.x * blockDim.x + threadIdx.x) >> 6;
  if (n >= n_nodes) return;
  const float dg = fmaxf(deg[n], 1.0f);
  const float hv = h[n * 64 + lane];
  const float a = agg[n * 64 + lane] / dg + hv;
  const float c = ln_apply(a, ng[lane], nb[lane]);
  const float o = ln_apply(c, og[lane], ob[lane]);
  h[n * 64 + lane] = hv + o;
}

// ------------------------------ pooling ------------------------------------
__global__ void k_pool(const float* __restrict__ h, const int* __restrict__ batch,
                       float* __restrict__ g, float* __restrict__ cnt, int n_nodes) {
  const int lane = threadIdx.x & 63;
  const int n = (blockIdx.x * blockDim.x + threadIdx.x) >> 6;
  if (n >= n_nodes) return;
  const int b = batch[n];
  atomicAdd(&g[b * 64 + lane], h[n * 64 + lane]);
  if (lane == 0) atomicAdd(&cnt[b], 1.0f);
}

// ------------------------------- head --------------------------------------
// relu(ln(g@W1+b1)) -> relu(ln(@W2+b2)) (width 32, duplicated in both wave
// halves so 64-lane LN reductions equal the 32-wide stats) -> @W3+b3.
__global__ void k_head(const float* __restrict__ g, const float* __restrict__ cnt,
                       const float* __restrict__ w1, const float* __restrict__ b1,
                       const float* __restrict__ g1, const float* __restrict__ be1,
                       const float* __restrict__ w2, const float* __restrict__ b2,
                       const float* __restrict__ g2, const float* __restrict__ be2,
                       const float* __restrict__ w3, const float* __restrict__ b3,
                       float* __restrict__ out, int nb_) {
  const int lane = threadIdx.x & 63;
  const int row = (blockIdx.x * blockDim.x + threadIdx.x) >> 6;
  if (row >= nb_) return;
  const float c = fmaxf(cnt[row], 1.0f);
  const float gv = g[row * 64 + lane] / c;
  float a0 = b1[lane], a1 = 0.f, a2 = 0.f, a3 = 0.f;
#pragma unroll
  for (int k = 0; k < 64; k += 4) {
    a0 = fmaf(lane_bcast(gv, k + 0), w1[(k + 0) * 64 + lane], a0);
    a1 = fmaf(lane_bcast(gv, k + 1), w1[(k + 1) * 64 + lane], a1);
    a2 = fmaf(lane_bcast(gv, k + 2), w1[(k + 2) * 64 + lane], a2);
    a3 = fmaf(lane_bcast(gv, k + 3), w1[(k + 3) * 64 + lane], a3);
  }
  float t = (a0 + a1) + (a2 + a3);
  t = fmaxf(ln_apply(t, g1[lane], be1[lane]), 0.0f);

  const int j = lane & 31;  // both wave halves compute the same 32 outputs
  float c0 = b2[j], c1 = 0.f, c2 = 0.f, c3 = 0.f;
#pragma unroll
  for (int k = 0; k < 64; k += 4) {
    c0 = fmaf(lane_bcast(t, k + 0), w2[(k + 0) * 32 + j], c0);
    c1 = fmaf(lane_bcast(t, k + 1), w2[(k + 1) * 32 + j], c1);
    c2 = fmaf(lane_bcast(t, k + 2), w2[(k + 2) * 32 + j], c2);
    c3 = fmaf(lane_bcast(t, k + 3), w2[(k + 3) * 32 + j], c3);
  }
  float t2 = (c0 + c1) + (c2 + c3);
  // lanes j and j+32 are identical -> 64-lane mean/var == 32-wide mean/var
  t2 = fmaxf(ln_apply(t2, g2[j], be2[j]), 0.0f);
  const float p = t2 * w3[j];
  const float s = wave_sum64(p) * 0.5f;  // sum64 = 2 * sum32
  if (lane == 0) out[row] = s + b3[0];
}

// ---------------------------------------------------------------------------
extern "C" void kernel_launch(void* const* d_in, const int* in_sizes, int n_in,
                              void* d_out, int out_size, void* d_ws, size_t ws_size,
                              hipStream_t stream) {
  const float* x      = (const float*)d_in[0];
  const float* ea     = (const float*)d_in[1];
  const float* ne_w1  = (const float*)d_in[2];
  const float* ne_b1  = (const float*)d_in[3];
  const float* ne_g1  = (const float*)d_in[4];
  const float* ne_be1 = (const float*)d_in[5];
  const float* ne_w2  = (const float*)d_in[6];
  const float* ne_b2  = (const float*)d_in[7];
  const float* ne_g2  = (const float*)d_in[8];
  const float* ne_be2 = (const float*)d_in[9];
  const float* conv_w = (const float*)d_in[10];
  const float* conv_b = (const float*)d_in[11];
  const float* conv_mg= (const float*)d_in[12];
  const float* conv_mb= (const float*)d_in[13];
  const float* conv_ng= (const float*)d_in[14];
  const float* conv_nb= (const float*)d_in[15];
  const float* out_ng = (const float*)d_in[16];
  const float* out_nb = (const float*)d_in[17];
  const float* m_w1   = (const float*)d_in[18];
  const float* m_b1   = (const float*)d_in[19];
  const float* m_g1   = (const float*)d_in[20];
  const float* m_be1  = (const float*)d_in[21];
  const float* m_w2   = (const float*)d_in[22];
  const float* m_b2   = (const float*)d_in[23];
  const float* m_g2   = (const float*)d_in[24];
  const float* m_be2  = (const float*)d_in[25];
  const float* m_w3   = (const float*)d_in[26];
  const float* m_b3   = (const float*)d_in[27];
  const int*   eidx   = (const int*)d_in[28];
  const int*   batch  = (const int*)d_in[29];
  float* outp = (float*)d_out;

  const int NN = in_sizes[29];      // N nodes (batch array length)
  const int NE = in_sizes[1] / 2;   // E edges (edge_attr is E x 2)
  const int NB = out_size;          // number of graphs (output is B x 1)

  float* ws = (float*)d_ws;
  float* h    = ws;                           // NN*64
  float* agg  = h + (size_t)NN * 64;          // NN*64
  float* deg  = agg + (size_t)NN * 64;        // NN
  float* gbuf = deg + NN;                     // NB*64
  float* cnt  = gbuf + (size_t)NB * 64;       // NB

  // zero deg + gbuf + cnt in one contiguous memset (ws is poisoned 0xAA)
  hipMemsetAsync(deg, 0, sizeof(float) * ((size_t)NN + (size_t)NB * 64 + NB), stream);

  const dim3 blk(256);
  k_node_embed<<<2048, blk, 0, stream>>>(x, ne_w1, ne_b1, ne_g1, ne_be1,
                                         ne_w2, ne_b2, ne_g2, ne_be2, h, NN);
  k_deg<<<(NE + 255) / 256, blk, 0, stream>>>(eidx, deg, NE);

  for (int l = 0; l < 3; l++) {
    hipMemsetAsync(agg, 0, sizeof(float) * (size_t)NN * 64, stream);
    k_edge<<<8192, blk, 0, stream>>>(h, ea, eidx,
                                     conv_w + (size_t)l * 66 * 64, conv_b + l * 64,
                                     conv_mg + l * 64, conv_mb + l * 64, agg, NE);
    k_node_update<<<(NN * 64 + 255) / 256, blk, 0, stream>>>(
        h, agg, deg, conv_ng + l * 64, conv_nb + l * 64,
        out_ng + l * 64, out_nb + l * 64, NN);
  }

  k_pool<<<(NN * 64 + 255) / 256, blk, 0, stream>>>(h, batch, gbuf, cnt, NN);
  k_head<<<(NB + 3) / 4, blk, 0, stream>>>(gbuf, cnt, m_w1, m_b1, m_g1, m_be1,
                                           m_w2, m_b2, m_g2, m_be2, m_w3, m_b3,
                                           outp, NB);
}

// Round 3
// 1401.714 us; speedup vs baseline: 1.6732x; 1.6732x over previous
//
#include <hip/hip_runtime.h>
#include <math.h>

// ---------------------------------------------------------------------------
// VertexGNN on MI355X — round 2: MFMA edge MLP, fp32-gather variant.
// 16 edges/wave as 16x96 @ 96x64 bf16 MFMA (K=64 h-gather + K=2 edge_attr +
// zero pad). h gathered as fp32 and converted in-register (no bf16 shadow --
// keeps workspace at the round-1-proven footprint + 36KB weight buffer).
// Fixed k_pool_seg grid (was launching 32 waves instead of 1563).
// ---------------------------------------------------------------------------

typedef __attribute__((ext_vector_type(8))) short bfrag;   // 8 x bf16
typedef __attribute__((ext_vector_type(4))) float ffrag;   // 4 x f32

__device__ __forceinline__ float wave_sum64(float v) {
#pragma unroll
  for (int m = 1; m < 64; m <<= 1) v += __shfl_xor(v, m, 64);
  return v;
}

// sum across the 16 consecutive lanes sharing lane>>4
__device__ __forceinline__ float rsum16(float v) {
#pragma unroll
  for (int m = 1; m < 16; m <<= 1) v += __shfl_xor(v, m, 64);
  return v;
}

__device__ __forceinline__ float ln_apply(float t, float g, float b) {
  float mu = wave_sum64(t) * 0.015625f;
  float d = t - mu;
  float var = wave_sum64(d * d) * 0.015625f;
  return d * rsqrtf(var + 1e-5f) * g + b;
}

__device__ __forceinline__ float gelu_exact(float v) {
  return 0.5f * v * (1.0f + erff(v * 0.70710678118654752440f));
}

__device__ __forceinline__ float lane_bcast(float v, int k) {
  return __uint_as_float(__builtin_amdgcn_readlane(__float_as_uint(v), k));
}

// float -> bf16 (RNE)
__device__ __forceinline__ short f2bf(float f) {
  union { float f; unsigned u; } v; v.f = f;
  unsigned r = v.u + 0x7fffu + ((v.u >> 16) & 1u);
  return (short)(r >> 16);
}

// --------------------------- weight prep -----------------------------------
// Wt[l][f][k] = (k<66 ? conv_w[l][k][f] : 0) as bf16; shape 3 x 64 x 96.
__global__ void k_prep_w(const float* __restrict__ conv_w, ushort* __restrict__ wt) {
  int i = blockIdx.x * blockDim.x + threadIdx.x;
  if (i >= 3 * 64 * 96) return;
  int k = i % 96, f = (i / 96) % 64, l = i / (96 * 64);
  float v = (k < 66) ? conv_w[(size_t)l * 66 * 64 + k * 64 + f] : 0.0f;
  wt[i] = (ushort)f2bf(v);
}

// --------------------------- node embedding --------------------------------
__global__ void k_node_embed(const float* __restrict__ x,
                             const float* __restrict__ w1, const float* __restrict__ b1,
                             const float* __restrict__ g1, const float* __restrict__ be1,
                             const float* __restrict__ w2, const float* __restrict__ b2,
                             const float* __restrict__ g2, const float* __restrict__ be2,
                             float* __restrict__ h, int n_nodes) {
  const int lane = threadIdx.x & 63;
  const int wid = (blockIdx.x * blockDim.x + threadIdx.x) >> 6;
  const int nw = (gridDim.x * blockDim.x) >> 6;
  float wc[64];
#pragma unroll
  for (int k = 0; k < 64; k++) wc[k] = w2[k * 64 + lane];
  const float w1a = w1[lane], w1b = w1[64 + lane];
  const float vb1 = b1[lane], vg1 = g1[lane], vbe1 = be1[lane];
  const float vb2 = b2[lane], vg2 = g2[lane], vbe2 = be2[lane];
  for (int n = wid; n < n_nodes; n += nw) {
    const float x0 = x[2 * n], x1 = x[2 * n + 1];
    float t = fmaf(x0, w1a, fmaf(x1, w1b, vb1));
    t = gelu_exact(ln_apply(t, vg1, vbe1));
    float a0 = vb2, a1 = 0.f, a2 = 0.f, a3 = 0.f;
#pragma unroll
    for (int k = 0; k < 64; k += 4) {
      a0 = fmaf(lane_bcast(t, k + 0), wc[k + 0], a0);
      a1 = fmaf(lane_bcast(t, k + 1), wc[k + 1], a1);
      a2 = fmaf(lane_bcast(t, k + 2), wc[k + 2], a2);
      a3 = fmaf(lane_bcast(t, k + 3), wc[k + 3], a3);
    }
    float acc = (a0 + a1) + (a2 + a3);
    acc = gelu_exact(ln_apply(acc, vg2, vbe2));
    h[n * 64 + lane] = acc;
  }
}

// ------------------------------ degree -------------------------------------
__global__ void k_deg(const int* __restrict__ ei, float* __restrict__ deg, int ne) {
  int i = blockIdx.x * blockDim.x + threadIdx.x;
  if (i < ne) atomicAdd(&deg[ei[ne + i]], 1.0f);
}

// --------------------- edge message (MFMA) + scatter ------------------------
// 16 edges per wave. A: 16x96 (rows=edges, k=[h[src](64) | ea(2) | pad]),
// B: Wt tiles 96x16. A-operand layout: A[m=lane&15][k=(lane>>4)*8+j].
// C tiles: row=edge=(lane>>4)*4+reg, col=f=16t+(lane&15).
__global__ __launch_bounds__(256) void k_edge_mfma(
    const float* __restrict__ h, const float* __restrict__ ea,
    const int* __restrict__ ei, const ushort* __restrict__ wt,
    const float* __restrict__ bias, const float* __restrict__ mg,
    const float* __restrict__ mb, float* __restrict__ agg, int ne) {
  const int lane = threadIdx.x & 63;
  const int grp = lane >> 4, col = lane & 15;
  const int wid = (blockIdx.x * blockDim.x + threadIdx.x) >> 6;
  const int nw = (gridDim.x * blockDim.x) >> 6;

  bfrag Bf[3][4];
#pragma unroll
  for (int s = 0; s < 3; s++)
#pragma unroll
    for (int t = 0; t < 4; t++)
      Bf[s][t] = *(const bfrag*)(wt + (size_t)(t * 16 + col) * 96 + s * 32 + grp * 8);

  float vb[4], vg[4], vbb[4];
#pragma unroll
  for (int t = 0; t < 4; t++) {
    vb[t] = bias[t * 16 + col];
    vg[t] = mg[t * 16 + col];
    vbb[t] = mb[t * 16 + col];
  }

  for (int e0 = wid * 16; e0 < ne; e0 += nw * 16) {
    // ---- A fragments: this lane feeds edge row m = col, k-slice grp*8.. ----
    const int eA = e0 + col;
    const int src = ei[eA];
    const float* hp = h + (size_t)src * 64 + grp * 8;
    const float4 f0 = *(const float4*)(hp);
    const float4 f1 = *(const float4*)(hp + 4);
    const float4 f2 = *(const float4*)(hp + 32);
    const float4 f3 = *(const float4*)(hp + 36);
    bfrag A0, A1;
    A0[0] = f2bf(f0.x); A0[1] = f2bf(f0.y); A0[2] = f2bf(f0.z); A0[3] = f2bf(f0.w);
    A0[4] = f2bf(f1.x); A0[5] = f2bf(f1.y); A0[6] = f2bf(f1.z); A0[7] = f2bf(f1.w);
    A1[0] = f2bf(f2.x); A1[1] = f2bf(f2.y); A1[2] = f2bf(f2.z); A1[3] = f2bf(f2.w);
    A1[4] = f2bf(f3.x); A1[5] = f2bf(f3.y); A1[6] = f2bf(f3.z); A1[7] = f2bf(f3.w);
    bfrag A2 = {0, 0, 0, 0, 0, 0, 0, 0};
    if (grp == 0) {
      const float2 eav = *(const float2*)(ea + 2 * (size_t)eA);
      A2[0] = f2bf(eav.x); A2[1] = f2bf(eav.y);
    }

    ffrag acc[4];
#pragma unroll
    for (int t = 0; t < 4; t++) { ffrag c = {vb[t], vb[t], vb[t], vb[t]}; acc[t] = c; }
#pragma unroll
    for (int t = 0; t < 4; t++)
      acc[t] = __builtin_amdgcn_mfma_f32_16x16x32_bf16(A0, Bf[0][t], acc[t], 0, 0, 0);
#pragma unroll
    for (int t = 0; t < 4; t++)
      acc[t] = __builtin_amdgcn_mfma_f32_16x16x32_bf16(A1, Bf[1][t], acc[t], 0, 0, 0);
#pragma unroll
    for (int t = 0; t < 4; t++)
      acc[t] = __builtin_amdgcn_mfma_f32_16x16x32_bf16(A2, Bf[2][t], acc[t], 0, 0, 0);

    // ---- LayerNorm over 64 features per edge row (rows m = grp*4+r) ----
    float mu[4], inv[4];
#pragma unroll
    for (int r = 0; r < 4; r++) {
      float s = ((acc[0][r] + acc[1][r]) + (acc[2][r] + acc[3][r]));
      mu[r] = rsum16(s) * 0.015625f;
    }
#pragma unroll
    for (int r = 0; r < 4; r++) {
      float d0 = acc[0][r] - mu[r], d1 = acc[1][r] - mu[r];
      float d2 = acc[2][r] - mu[r], d3 = acc[3][r] - mu[r];
      float q = (d0 * d0 + d1 * d1) + (d2 * d2 + d3 * d3);
      inv[r] = rsqrtf(rsum16(q) * 0.015625f + 1e-5f);
    }

    int dst[4];
#pragma unroll
    for (int r = 0; r < 4; r++) dst[r] = ei[ne + e0 + grp * 4 + r];

#pragma unroll
    for (int r = 0; r < 4; r++) {
#pragma unroll
      for (int t = 0; t < 4; t++) {
        float v = (acc[t][r] - mu[r]) * inv[r] * vg[t] + vbb[t];
        v = gelu_exact(v);
        atomicAdd(&agg[(size_t)dst[r] * 64 + t * 16 + col], v);
      }
    }
  }
}

// --------------------------- node update -----------------------------------
__global__ void k_node_update(float* __restrict__ h, const float* __restrict__ agg,
                              const float* __restrict__ deg,
                              const float* __restrict__ ng, const float* __restrict__ nb,
                              const float* __restrict__ og, const float* __restrict__ ob,
                              int n_nodes) {
  const int lane = threadIdx.x & 63;
  const int n = (blockIdx.x * blockDim.x + threadIdx.x) >> 6;
  if (n >= n_nodes) return;
  const float dg = fmaxf(deg[n], 1.0f);
  const float hv = h[n * 64 + lane];
  const float a = agg[n * 64 + lane] / dg + hv;
  const float c = ln_apply(a, ng[lane], nb[lane]);
  const float o = ln_apply(c, og[lane], ob[lane]);
  h[n * 64 + lane] = hv + o;
}

// ------------------------------ pooling (segmented) -------------------------
// batch is sorted: accumulate runs in registers, flush once per graph change.
__global__ void k_pool_seg(const float* __restrict__ h, const int* __restrict__ batch,
                           float* __restrict__ g, float* __restrict__ cnt,
                           int n_nodes, int chunk) {
  const int lane = threadIdx.x & 63;
  const int wid = (blockIdx.x * blockDim.x + threadIdx.x) >> 6;
  const int n0 = wid * chunk;
  if (n0 >= n_nodes) return;
  const int n1 = min(n0 + chunk, n_nodes);
  int cur = batch[n0], c = 0;
  float acc = 0.f;
  for (int n = n0; n < n1; n++) {
    const int b = batch[n];
    if (b != cur) {
      atomicAdd(&g[(size_t)cur * 64 + lane], acc);
      if (lane == 0) atomicAdd(&cnt[cur], (float)c);
      acc = 0.f; c = 0; cur = b;
    }
    acc += h[(size_t)n * 64 + lane];
    c++;
  }
  atomicAdd(&g[(size_t)cur * 64 + lane], acc);
  if (lane == 0) atomicAdd(&cnt[cur], (float)c);
}

// ------------------------------- head --------------------------------------
__global__ void k_head(const float* __restrict__ g, const float* __restrict__ cnt,
                       const float* __restrict__ w1, const float* __restrict__ b1,
                       const float* __restrict__ g1, const float* __restrict__ be1,
                       const float* __restrict__ w2, const float* __restrict__ b2,
                       const float* __restrict__ g2, const float* __restrict__ be2,
                       const float* __restrict__ w3, const float* __restrict__ b3,
                       float* __restrict__ out, int nb_) {
  const int lane = threadIdx.x & 63;
  const int row = (blockIdx.x * blockDim.x + threadIdx.x) >> 6;
  if (row >= nb_) return;
  const float c = fmaxf(cnt[row], 1.0f);
  const float gv = g[row * 64 + lane] / c;
  float a0 = b1[lane], a1 = 0.f, a2 = 0.f, a3 = 0.f;
#pragma unroll
  for (int k = 0; k < 64; k += 4) {
    a0 = fmaf(lane_bcast(gv, k + 0), w1[(k + 0) * 64 + lane], a0);
    a1 = fmaf(lane_bcast(gv, k + 1), w1[(k + 1) * 64 + lane], a1);
    a2 = fmaf(lane_bcast(gv, k + 2), w1[(k + 2) * 64 + lane], a2);
    a3 = fmaf(lane_bcast(gv, k + 3), w1[(k + 3) * 64 + lane], a3);
  }
  float t = (a0 + a1) + (a2 + a3);
  t = fmaxf(ln_apply(t, g1[lane], be1[lane]), 0.0f);

  const int j = lane & 31;
  float c0 = b2[j], c1 = 0.f, c2 = 0.f, c3 = 0.f;
#pragma unroll
  for (int k = 0; k < 64; k += 4) {
    c0 = fmaf(lane_bcast(t, k + 0), w2[(k + 0) * 32 + j], c0);
    c1 = fmaf(lane_bcast(t, k + 1), w2[(k + 1) * 32 + j], c1);
    c2 = fmaf(lane_bcast(t, k + 2), w2[(k + 2) * 32 + j], c2);
    c3 = fmaf(lane_bcast(t, k + 3), w2[(k + 3) * 32 + j], c3);
  }
  float t2 = (c0 + c1) + (c2 + c3);
  t2 = fmaxf(ln_apply(t2, g2[j], be2[j]), 0.0f);
  const float p = t2 * w3[j];
  const float s = wave_sum64(p) * 0.5f;
  if (lane == 0) out[row] = s + b3[0];
}

// ---------------------------------------------------------------------------
extern "C" void kernel_launch(void* const* d_in, const int* in_sizes, int n_in,
                              void* d_out, int out_size, void* d_ws, size_t ws_size,
                              hipStream_t stream) {
  const float* x      = (const float*)d_in[0];
  const float* ea     = (const float*)d_in[1];
  const float* ne_w1  = (const float*)d_in[2];
  const float* ne_b1  = (const float*)d_in[3];
  const float* ne_g1  = (const float*)d_in[4];
  const float* ne_be1 = (const float*)d_in[5];
  const float* ne_w2  = (const float*)d_in[6];
  const float* ne_b2  = (const float*)d_in[7];
  const float* ne_g2  = (const float*)d_in[8];
  const float* ne_be2 = (const float*)d_in[9];
  const float* conv_w = (const float*)d_in[10];
  const float* conv_b = (const float*)d_in[11];
  const float* conv_mg= (const float*)d_in[12];
  const float* conv_mb= (const float*)d_in[13];
  const float* conv_ng= (const float*)d_in[14];
  const float* conv_nb= (const float*)d_in[15];
  const float* out_ng = (const float*)d_in[16];
  const float* out_nb = (const float*)d_in[17];
  const float* m_w1   = (const float*)d_in[18];
  const float* m_b1   = (const float*)d_in[19];
  const float* m_g1   = (const float*)d_in[20];
  const float* m_be1  = (const float*)d_in[21];
  const float* m_w2   = (const float*)d_in[22];
  const float* m_b2   = (const float*)d_in[23];
  const float* m_g2   = (const float*)d_in[24];
  const float* m_be2  = (const float*)d_in[25];
  const float* m_w3   = (const float*)d_in[26];
  const float* m_b3   = (const float*)d_in[27];
  const int*   eidx   = (const int*)d_in[28];
  const int*   batch  = (const int*)d_in[29];
  float* outp = (float*)d_out;

  const int NN = in_sizes[29];
  const int NE = in_sizes[1] / 2;
  const int NB = out_size;

  float* ws = (float*)d_ws;
  float*  h    = ws;                                  // NN*64 f32
  float*  agg  = h + (size_t)NN * 64;                 // NN*64 f32
  float*  deg  = agg + (size_t)NN * 64;               // NN f32
  float*  gbuf = deg + NN;                            // NB*64 f32
  float*  cnt  = gbuf + (size_t)NB * 64;              // NB f32
  ushort* wt   = (ushort*)(cnt + NB);                 // 3*64*96 bf16 (36 KB)

  hipMemsetAsync(deg, 0, sizeof(float) * ((size_t)NN + (size_t)NB * 64 + NB), stream);

  const dim3 blk(256);
  k_prep_w<<<(3 * 64 * 96 + 255) / 256, blk, 0, stream>>>(conv_w, wt);
  k_node_embed<<<2048, blk, 0, stream>>>(x, ne_w1, ne_b1, ne_g1, ne_be1,
                                         ne_w2, ne_b2, ne_g2, ne_be2, h, NN);
  k_deg<<<(NE + 255) / 256, blk, 0, stream>>>(eidx, deg, NE);

  for (int l = 0; l < 3; l++) {
    hipMemsetAsync(agg, 0, sizeof(float) * (size_t)NN * 64, stream);
    k_edge_mfma<<<4096, blk, 0, stream>>>(h, ea, eidx, wt + (size_t)l * 64 * 96,
                                          conv_b + l * 64, conv_mg + l * 64,
                                          conv_mb + l * 64, agg, NE);
    k_node_update<<<(NN * 64 + 255) / 256, blk, 0, stream>>>(
        h, agg, deg, conv_ng + l * 64, conv_nb + l * 64,
        out_ng + l * 64, out_nb + l * 64, NN);
  }

  // pooling: one wave per 64-node chunk; waves = ceil(NN/64)
  {
    const int chunk = 64;
    const int nwaves = (NN + chunk - 1) / chunk;
    const int nblocks = (nwaves * 64 + 255) / 256;
    k_pool_seg<<<nblocks, blk, 0, stream>>>(h, batch, gbuf, cnt, NN, chunk);
  }
  k_head<<<(NB + 3) / 4, blk, 0, stream>>>(gbuf, cnt, m_w1, m_b1, m_g1, m_be1,
                                           m_w2, m_b2, m_g2, m_be2, m_w3, m_b3,
                                           outp, NB);
}